// Round 5
// baseline (149.737 us; speedup 1.0000x reference)
//
#include <hip/hip_runtime.h>
#include <hip/hip_bf16.h>
#include <cstdint>

#define B_ROWS 4096
#define DIM 1024
#define NN 8192  // 2*B

typedef int v4i __attribute__((ext_vector_type(4)));
typedef int v16i __attribute__((ext_vector_type(16)));

__device__ __forceinline__ float wave_reduce_sum(float v) {
    v += __shfl_xor(v, 1);
    v += __shfl_xor(v, 2);
    v += __shfl_xor(v, 4);
    v += __shfl_xor(v, 8);
    v += __shfl_xor(v, 16);
    v += __shfl_xor(v, 32);
    return v;
}

__device__ __forceinline__ void gld_lds16(const void* g, void* l) {
    __builtin_amdgcn_global_load_lds(
        (__attribute__((address_space(1))) void*)(uintptr_t)g,
        (__attribute__((address_space(3))) void*)l, 16, 0, 0);
}

// Kernel 1: L2-normalize + positives, ONE WAVE PER ROW-PAIR. No LDS/barriers.
// rep is SIGNED i8: round(127 * normalized). |x̂| <= ~0.16 for N(0,1) data at
// D=1024, so no clamp needed; i32 MFMA accumulation is exact.
__global__ void norm_pos_kernel(const float* __restrict__ p1,
                                const float* __restrict__ p2,
                                signed char* __restrict__ rep,
                                float* __restrict__ pos) {
    const int wv = threadIdx.x >> 6, lane = threadIdx.x & 63;
    const int i = blockIdx.x * 4 + wv;  // 0..4095
    const float4* ap = (const float4*)(p1 + (size_t)i * DIM);
    const float4* bp = (const float4*)(p2 + (size_t)i * DIM);
    float4 a[4], b[4];
#pragma unroll
    for (int c = 0; c < 4; ++c) { a[c] = ap[lane + 64 * c]; b[c] = bp[lane + 64 * c]; }
    float s1 = 0.f, s2 = 0.f, dp = 0.f;
#pragma unroll
    for (int c = 0; c < 4; ++c) {
        s1 += a[c].x * a[c].x + a[c].y * a[c].y + a[c].z * a[c].z + a[c].w * a[c].w;
        s2 += b[c].x * b[c].x + b[c].y * b[c].y + b[c].z * b[c].z + b[c].w * b[c].w;
        dp += a[c].x * b[c].x + a[c].y * b[c].y + a[c].z * b[c].z + a[c].w * b[c].w;
    }
    s1 = wave_reduce_sum(s1);
    s2 = wave_reduce_sum(s2);
    dp = wave_reduce_sum(dp);
    const float sc1 = rsqrtf(s1) * 127.0f, sc2 = rsqrtf(s2) * 127.0f;
    char4* o1 = (char4*)(rep + (size_t)i * DIM);
    char4* o2 = (char4*)(rep + (size_t)(i + B_ROWS) * DIM);
#pragma unroll
    for (int c = 0; c < 4; ++c) {
        char4 u1, u2;
        u1.x = (signed char)__float2int_rn(a[c].x * sc1);
        u1.y = (signed char)__float2int_rn(a[c].y * sc1);
        u1.z = (signed char)__float2int_rn(a[c].z * sc1);
        u1.w = (signed char)__float2int_rn(a[c].w * sc1);
        u2.x = (signed char)__float2int_rn(b[c].x * sc2);
        u2.y = (signed char)__float2int_rn(b[c].y * sc2);
        u2.z = (signed char)__float2int_rn(b[c].z * sc2);
        u2.w = (signed char)__float2int_rn(b[c].w * sc2);
        o1[lane + 64 * c] = u1;
        o2[lane + 64 * c] = u2;
    }
    if (lane == 0) pos[i] = dp * rsqrtf(s1) * rsqrtf(s2);
}

// Kernel 2 (R21): 128x128 triangle tiles, 2x2 waves of 64x64, MFMA shape
// switched 16x16x64 -> 32x32x32 i8: HALF the MFMA instructions at the same
// total OPs (+12% ubench per-OP: 4404 vs 3944 TOPS).
//
// WHY: R0-R4 = five structurally distinct schedules (drain barriers, 2-phase
// dbuf, counted-vmcnt depth-2, fat 64x128 tile, m201 fine-phased) all land
// at 56-59 us, MfmaUtil ~24%. Normalized per-MFMA-INSTRUCTION cost is
// invariant: 16.5 CU-cy (R0) vs 16.0 CU-cy (R4) = 3.1x the ubench 5.1
// CU-cy, across tile shapes, occupancies, schedules. Schedule is exonerated;
// the cost is tied to the instruction stream. This round discriminates
// per-instruction vs per-OP: halving instruction count at constant OPs
// -> time halves if per-instruction (H-instr), flat if per-OP (H-op).
//
// Fragment layout (square-shape-symmetric generalization of the verified
// 16x16x64 pattern): A/B lane l holds row/col (l&31), 16-byte k-chunk
// (l>>5); K-tile 64 = 2 MFMA k-steps x 2 chunks. A and B agree on the
// lane->k mapping, so the staged-seg XOR de-swizzle (read seg s of row w at
// slot s^((w>>1)&3)) keeps the contraction exact, as in R0-R4.
// C/D (m74/m101, dtype-independent): col = lane&31,
// row = (reg&3) + 8*(reg>>2) + 4*(lane>>5), reg in [0,16).
//
// Geometry: triangle (rb<=cb) of 128x128 tiles = 2080 blocks; 48 KB LDS
// (3 buffers), __launch_bounds__(256,3) -> 3 blocks/CU, 12 waves/CU,
// tail-skew 2080/768 = 2.71 -> 3 rounds (1.11x, vs R4's 1.21x).
// Schedule: R2's verified counted-vmcnt loop (simplest of the proven-equal).
__global__ __launch_bounds__(256, 3) void gemm_kernel(const signed char* __restrict__ rep,
                                                      float* __restrict__ partial) {
    // XCD-chunked swizzle (2080 = 8*260, bijective)
    const int bid0 = blockIdx.x;
    const int bid = (bid0 & 7) * 260 + (bid0 >> 3);
    // rb-major triangle decode: start(rb) = 64*rb - rb*(rb-1)/2
    int rb = (int)(64.5f - sqrtf(4160.25f - 2.0f * (float)bid));
    while (64 * (rb + 1) - (rb + 1) * rb / 2 <= bid) ++rb;
    while (64 * rb - rb * (rb - 1) / 2 > bid) --rb;
    const int cb = rb + (bid - (64 * rb - rb * (rb - 1) / 2));

    __shared__ __align__(16) signed char As[3][8192];  // 24 KB (128 rows x 64)
    __shared__ __align__(16) signed char Bs[3][8192];  // 24 KB
    const int t = threadIdx.x;
    const int lane = t & 63;
    const int wv = t >> 6;      // 0..3
    const int wr = wv >> 1;     // wave row-half
    const int wc = wv & 1;      // wave col-half
    const int rr = lane & 31;   // frag row/col index
    const int h = lane >> 5;    // frag 16B k-chunk

    // staging source (unchanged from R0-R4): thread t -> row t>>2,
    // global seg (t&3)^((row>>1)&3), LDS slot t*16.
    const int sr = t >> 2;
    const int sg = (t & 3) ^ ((sr >> 1) & 3);
    const signed char* aS = rep + (size_t)(rb * 128 + sr) * DIM + sg * 16;
    const signed char* bS = rep + (size_t)(cb * 128 + sr) * DIM + sg * 16;

    // fragment read offsets. Row r = g*64 + w (g = wr or wc, w = mi*32+rr);
    // seg s = ks*2 + h lives at slot s ^ ((w>>1)&3); mi*32 is 0 mod 4 so
    // fsw = (rr>>1)&3 is mi-invariant.
    const int fsw = (rr >> 1) & 3;
    int aRow[2], bRow[2], segO[2];
#pragma unroll
    for (int mi = 0; mi < 2; ++mi) aRow[mi] = wr * 4096 + (mi * 32 + rr) * 64;
#pragma unroll
    for (int ni = 0; ni < 2; ++ni) bRow[ni] = wc * 4096 + (ni * 32 + rr) * 64;
#pragma unroll
    for (int ks = 0; ks < 2; ++ks) segO[ks] = ((ks * 2 + h) ^ fsw) << 4;

    v16i acc[2][2];
#pragma unroll
    for (int i = 0; i < 2; ++i)
#pragma unroll
        for (int j = 0; j < 2; ++j)
#pragma unroll
            for (int e = 0; e < 16; ++e) acc[i][j][e] = 0;

    auto STAGE = [&](signed char* Ad, signed char* Bd, int kk) {
        const signed char* a0 = aS + kk * 64;
        const signed char* b0 = bS + kk * 64;
        gld_lds16(a0, Ad + t * 16);                            // A rows 0..63
        gld_lds16(a0 + (size_t)64 * DIM, Ad + t * 16 + 4096);  // A rows 64..127
        gld_lds16(b0, Bd + t * 16);
        gld_lds16(b0 + (size_t)64 * DIM, Bd + t * 16 + 4096);
    };

    auto COMPUTE = [&](const signed char* Ab, const signed char* Bb) {
#pragma unroll
        for (int ks = 0; ks < 2; ++ks) {
            v4i af[2], bf[2];
#pragma unroll
            for (int mi = 0; mi < 2; ++mi)
                af[mi] = *(const v4i*)(Ab + aRow[mi] + segO[ks]);
#pragma unroll
            for (int ni = 0; ni < 2; ++ni)
                bf[ni] = *(const v4i*)(Bb + bRow[ni] + segO[ks]);
#pragma unroll
            for (int mi = 0; mi < 2; ++mi)
#pragma unroll
                for (int ni = 0; ni < 2; ++ni)
                    acc[mi][ni] = __builtin_amdgcn_mfma_i32_32x32x32_i8(
                        af[mi], bf[ni], acc[mi][ni], 0, 0, 0);
        }
    };

    // Prologue: stage tiles 0 and 1 (8 loads in flight).
    STAGE(As[0], Bs[0], 0);
    STAGE(As[1], Bs[1], 1);

#pragma unroll
    for (int kk = 0; kk < 14; ++kk) {
        asm volatile("s_waitcnt vmcnt(4)" ::: "memory");  // own tile done; newest in flight
        __builtin_amdgcn_s_barrier();
        STAGE(As[(kk + 2) % 3], Bs[(kk + 2) % 3], kk + 2);
        COMPUTE(As[kk % 3], Bs[kk % 3]);
    }
    asm volatile("s_waitcnt vmcnt(4)" ::: "memory");
    __builtin_amdgcn_s_barrier();
    COMPUTE(As[14 % 3], Bs[14 % 3]);
    asm volatile("s_waitcnt vmcnt(0)" ::: "memory");
    __builtin_amdgcn_s_barrier();
    COMPUTE(As[15 % 3], Bs[15 % 3]);

    // Epilogue. C/D: col = ni*32 + rr, row = wv-tile + mi*32 + (reg&3) +
    // 8*(reg>>2) + 4*h. sim = acc/127^2; exp(sim*2). Rowsum -> slot 2cb+wc;
    // colsum -> slot 2rb+wr (off-diag blocks only). Row r of block i
    // receives slots {2c,2c+1: c>=i} u {2c,2c+1: c<i} = all 128, disjoint.
    const float esc = 2.0f / 16129.0f;  // (1/T) / 127^2
    float colsum[2];
    colsum[0] = 0.f; colsum[1] = 0.f;

#pragma unroll
    for (int mi = 0; mi < 2; ++mi) {
#pragma unroll
        for (int reg = 0; reg < 16; ++reg) {
            const int grow =
                rb * 128 + wr * 64 + mi * 32 + (reg & 3) + 8 * (reg >> 2) + 4 * h;
            float rs = 0.f;
#pragma unroll
            for (int ni = 0; ni < 2; ++ni) {
                const int gcol = cb * 128 + wc * 64 + ni * 32 + rr;
                const float e =
                    (grow == gcol) ? 0.f : __expf((float)acc[mi][ni][reg] * esc);
                rs += e;
                colsum[ni] += e;
            }
            rs += __shfl_xor(rs, 1);
            rs += __shfl_xor(rs, 2);
            rs += __shfl_xor(rs, 4);
            rs += __shfl_xor(rs, 8);
            rs += __shfl_xor(rs, 16);  // reduce within 32-lane group (same h)
            if (rr == 0) partial[(size_t)(2 * cb + wc) * NN + grow] = rs;
        }
    }

    if (rb != cb) {
#pragma unroll
        for (int ni = 0; ni < 2; ++ni) colsum[ni] += __shfl_xor(colsum[ni], 32);
        if (h == 0) {
#pragma unroll
            for (int ni = 0; ni < 2; ++ni)
                partial[(size_t)(2 * rb + wr) * NN + cb * 128 + wc * 64 + ni * 32 + rr] =
                    colsum[ni];
        }
    }
}

// Kernel 3: per-row denom -> per-row loss -> 64 block sums. 2 threads/row.
__global__ void reduce_rows_kernel(const float* __restrict__ partial,
                                   const float* __restrict__ pos,
                                   float* __restrict__ bsum) {
    const int g = blockIdx.x * 256 + threadIdx.x;  // 64 x 256 = 16384
    const int r = g >> 1;
    const int half = g & 1;
    float s0 = 0.f, s1 = 0.f, s2 = 0.f, s3 = 0.f;
    for (int kb = half * 64; kb < half * 64 + 64; kb += 4) {
        s0 += partial[(size_t)(kb + 0) * NN + r];
        s1 += partial[(size_t)(kb + 1) * NN + r];
        s2 += partial[(size_t)(kb + 2) * NN + r];
        s3 += partial[(size_t)(kb + 3) * NN + r];
    }
    float s = (s0 + s1) + (s2 + s3);
    s += __shfl_xor(s, 1);  // both lanes of the pair hold the full row sum
    float v = __logf(s) - pos[r & (B_ROWS - 1)] * 2.0f;  // counted twice; *0.5 below
    v = wave_reduce_sum(v);
    __shared__ float red[4];
    const int lane = threadIdx.x & 63, wv = threadIdx.x >> 6;
    if (lane == 0) red[wv] = v;
    __syncthreads();
    if (threadIdx.x == 0)
        bsum[blockIdx.x] = (red[0] + red[1] + red[2] + red[3]) * 0.5f;
}

// Kernel 4: final scalar
__global__ void final_kernel(const float* __restrict__ bsum,
                             float* __restrict__ out) {
    float s = bsum[threadIdx.x];
    s = wave_reduce_sum(s);
    if (threadIdx.x == 0) out[0] = s * (1.0f / NN);
}

extern "C" void kernel_launch(void* const* d_in, const int* in_sizes, int n_in,
                              void* d_out, int out_size, void* d_ws, size_t ws_size,
                              hipStream_t stream) {
    const float* p1 = (const float*)d_in[0];
    const float* p2 = (const float*)d_in[1];
    char* ws = (char*)d_ws;
    signed char* rep = (signed char*)ws;                      // 8 MiB (i8)
    float* partial = (float*)(ws + (size_t)8 * 1024 * 1024);  // 4 MiB (128 x 8192)
    float* pos = (float*)(ws + (size_t)12 * 1024 * 1024);     // 16 KiB
    float* bsum = (float*)(ws + (size_t)12 * 1024 * 1024 + 16384);  // 256 B
    float* out = (float*)d_out;

    norm_pos_kernel<<<1024, 256, 0, stream>>>(p1, p2, rep, pos);
    gemm_kernel<<<2080, 256, 0, stream>>>(rep, partial);
    reduce_rows_kernel<<<64, 256, 0, stream>>>(partial, pos, bsum);
    final_kernel<<<1, 64, 0, stream>>>(bsum, out);
}

// Round 6
// 133.944 us; speedup vs baseline: 1.1179x; 1.1179x over previous
//
#include <hip/hip_runtime.h>
#include <hip/hip_bf16.h>
#include <cstdint>

#define B_ROWS 4096
#define DIM 1024
#define NN 8192  // 2*B

typedef int v4i __attribute__((ext_vector_type(4)));

__device__ __forceinline__ float wave_reduce_sum(float v) {
    v += __shfl_xor(v, 1);
    v += __shfl_xor(v, 2);
    v += __shfl_xor(v, 4);
    v += __shfl_xor(v, 8);
    v += __shfl_xor(v, 16);
    v += __shfl_xor(v, 32);
    return v;
}

__device__ __forceinline__ void gld_lds16(const void* g, void* l) {
    __builtin_amdgcn_global_load_lds(
        (__attribute__((address_space(1))) void*)(uintptr_t)g,
        (__attribute__((address_space(3))) void*)l, 16, 0, 0);
}

// Kernel 1: L2-normalize + positives, ONE WAVE PER ROW-PAIR. No LDS/barriers.
// rep is SIGNED i8: round(127 * normalized). |x̂| <= ~0.16 for N(0,1) data at
// D=1024, so no clamp needed; i32 MFMA accumulation is exact.
__global__ void norm_pos_kernel(const float* __restrict__ p1,
                                const float* __restrict__ p2,
                                signed char* __restrict__ rep,
                                float* __restrict__ pos) {
    const int wv = threadIdx.x >> 6, lane = threadIdx.x & 63;
    const int i = blockIdx.x * 4 + wv;  // 0..4095
    const float4* ap = (const float4*)(p1 + (size_t)i * DIM);
    const float4* bp = (const float4*)(p2 + (size_t)i * DIM);
    float4 a[4], b[4];
#pragma unroll
    for (int c = 0; c < 4; ++c) { a[c] = ap[lane + 64 * c]; b[c] = bp[lane + 64 * c]; }
    float s1 = 0.f, s2 = 0.f, dp = 0.f;
#pragma unroll
    for (int c = 0; c < 4; ++c) {
        s1 += a[c].x * a[c].x + a[c].y * a[c].y + a[c].z * a[c].z + a[c].w * a[c].w;
        s2 += b[c].x * b[c].x + b[c].y * b[c].y + b[c].z * b[c].z + b[c].w * b[c].w;
        dp += a[c].x * b[c].x + a[c].y * b[c].y + a[c].z * b[c].z + a[c].w * b[c].w;
    }
    s1 = wave_reduce_sum(s1);
    s2 = wave_reduce_sum(s2);
    dp = wave_reduce_sum(dp);
    const float sc1 = rsqrtf(s1) * 127.0f, sc2 = rsqrtf(s2) * 127.0f;
    char4* o1 = (char4*)(rep + (size_t)i * DIM);
    char4* o2 = (char4*)(rep + (size_t)(i + B_ROWS) * DIM);
#pragma unroll
    for (int c = 0; c < 4; ++c) {
        char4 u1, u2;
        u1.x = (signed char)__float2int_rn(a[c].x * sc1);
        u1.y = (signed char)__float2int_rn(a[c].y * sc1);
        u1.z = (signed char)__float2int_rn(a[c].z * sc1);
        u1.w = (signed char)__float2int_rn(a[c].w * sc1);
        u2.x = (signed char)__float2int_rn(b[c].x * sc2);
        u2.y = (signed char)__float2int_rn(b[c].y * sc2);
        u2.z = (signed char)__float2int_rn(b[c].z * sc2);
        u2.w = (signed char)__float2int_rn(b[c].w * sc2);
        o1[lane + 64 * c] = u1;
        o2[lane + 64 * c] = u2;
    }
    if (lane == 0) pos[i] = dp * rsqrtf(s1) * rsqrtf(s2);
}

// Kernel 2 (R22): R0's proven geometry (128x128 triangle tiles, 2x2 waves,
// mfma_i32_16x16x64_i8, 0 bank conflicts) + counted-vmcnt depth-2 loop +
// *** BAND-ORDERED L2-RESIDENT TILE WALK (the new change) ***.
//
// WHY: six rounds of schedule/shape variation all land 56-70us. Per-CU pipe
// accounting across rounds: wall ~= SERIAL sum {staging-delivery ~58K cy,
// ds_read 50K, MFMA 42K} — pipes never overlap, and the LARGEST term is
// staging delivery: 532 MB/dispatch flows L2/L3->LDS, but rep (8 MB) >
// 4 MiB per-XCD L2, so B panels stream from L3 (~700-900 cy) every use
// (cb sweeps 40-64 panels per rb = 5-8 MB working set; this is why R1's
// plain XCD swizzle was null). Fix: walk the triangle in BANDS of 8 rb,
// cb-major within a band. The ~96 co-resident bids per XCD (32 CU x 3
// blocks, contiguous in the new order) then touch 8 A-panels (1 MB, hot
// for the whole band) + ~12 B-panels (1.5 MB) = ~2.5 MB < 4 MB L2. Each
// B panel is fetched from L3 once per band per XCD; delivery becomes
// L2-hit (~250 cy < compute phase) so the depth-2 prefetch can hide it.
//
// Band-order: band b = rb in [8b,8b+8). count(b) = 484-64b. Within band,
// cb ascending, rb ascending within cb: cb=8b+k (k=0..6) have k+1 tiles
// (the diagonal part, 28 total); cb>=8b+7 have 8 each.
//
// K-perm trick (unchanged): lane (cm,q) reads seg (q^fsw); A-lane and
// B-lane hold the same 16 global-k bytes in the same order -> contraction
// invariant. Staging: thread t -> row t>>2, global seg (t&3)^((sr>>1)&3),
// LDS slot t*16. 3 buffers, depth-2 prefetch, counted vmcnt(4).
__global__ __launch_bounds__(256, 3) void gemm_kernel(const signed char* __restrict__ rep,
                                                      float* __restrict__ partial) {
    // XCD-chunked swizzle (2080 = 8*260): each XCD gets a CONTIGUOUS 260-run
    // of the band-ordered sequence.
    const int bid0 = blockIdx.x;
    const int bid = (bid0 & 7) * 260 + (bid0 >> 3);
    // band-ordered decode
    int b = 0, S = 0;
    while (S + (484 - 64 * b) <= bid) { S += 484 - 64 * b; ++b; }
    const int w = bid - S;
    int rb, cb;
    if (w < 28) {  // diagonal-adjacent part: cb = 8b+k, k+1 tiles
        int k = 0;
        while ((k + 1) * (k + 2) / 2 <= w) ++k;
        rb = 8 * b + (w - k * (k + 1) / 2);
        cb = 8 * b + k;
    } else {  // full columns of 8
        const int u = w - 28;
        cb = 8 * b + 7 + (u >> 3);
        rb = 8 * b + (u & 7);
    }

    __shared__ __align__(16) signed char As[3][8192];  // 24 KB
    __shared__ __align__(16) signed char Bs[3][8192];  // 24 KB
    const int t = threadIdx.x;
    const int lane = t & 63;
    const int wv = t >> 6;     // 0..3
    const int wr = wv >> 1;    // wave row-half
    const int wc = wv & 1;     // wave col-half
    const int cm = lane & 15;  // frag m,n index
    const int q = lane >> 4;   // frag k-quarter

    // staging source
    const int sr = t >> 2;
    const int sg = (t & 3) ^ ((sr >> 1) & 3);
    const signed char* aS = rep + (size_t)(rb * 128 + sr) * DIM + sg * 16;
    const signed char* bS = rep + (size_t)(cb * 128 + sr) * DIM + sg * 16;

    // fragment read offsets (k-invariant): row cm within 64-row group, slot q^fsw
    const int fsw = (cm >> 1) & 3;
    const int aOff = wr * 4096 + cm * 64 + ((q ^ fsw) << 4);
    const int bOff = wc * 4096 + cm * 64 + ((q ^ fsw) << 4);

    v4i acc[4][4];
#pragma unroll
    for (int i = 0; i < 4; ++i)
#pragma unroll
        for (int j = 0; j < 4; ++j) acc[i][j] = (v4i){0, 0, 0, 0};

    auto STAGE = [&](signed char* Ad, signed char* Bd, int kk) {
        const signed char* a0 = aS + kk * 64;
        const signed char* b0 = bS + kk * 64;
        gld_lds16(a0, Ad + t * 16);                            // A rows 0..63
        gld_lds16(a0 + (size_t)64 * DIM, Ad + t * 16 + 4096);  // A rows 64..127
        gld_lds16(b0, Bd + t * 16);
        gld_lds16(b0 + (size_t)64 * DIM, Bd + t * 16 + 4096);
    };

    auto COMPUTE = [&](const signed char* Ab, const signed char* Bb) {
        v4i af[4], bf[4];
#pragma unroll
        for (int mi = 0; mi < 4; ++mi) af[mi] = *(const v4i*)(Ab + aOff + mi * 1024);
#pragma unroll
        for (int ni = 0; ni < 4; ++ni) bf[ni] = *(const v4i*)(Bb + bOff + ni * 1024);
#pragma unroll
        for (int mi = 0; mi < 4; ++mi)
#pragma unroll
            for (int ni = 0; ni < 4; ++ni)
                acc[mi][ni] = __builtin_amdgcn_mfma_i32_16x16x64_i8(
                    af[mi], bf[ni], acc[mi][ni], 0, 0, 0);
    };

    // Prologue: stage tiles 0 and 1 (8 loads in flight).
    STAGE(As[0], Bs[0], 0);
    STAGE(As[1], Bs[1], 1);

#pragma unroll
    for (int kk = 0; kk < 14; ++kk) {
        asm volatile("s_waitcnt vmcnt(4)" ::: "memory");  // own tile done; newest in flight
        __builtin_amdgcn_s_barrier();
        STAGE(As[(kk + 2) % 3], Bs[(kk + 2) % 3], kk + 2);
        COMPUTE(As[kk % 3], Bs[kk % 3]);
    }
    asm volatile("s_waitcnt vmcnt(4)" ::: "memory");
    __builtin_amdgcn_s_barrier();
    COMPUTE(As[14 % 3], Bs[14 % 3]);
    asm volatile("s_waitcnt vmcnt(0)" ::: "memory");
    __builtin_amdgcn_s_barrier();
    COMPUTE(As[15 % 3], Bs[15 % 3]);

    // Epilogue. C/D layout: col = wc*64 + ni*16 + cm, row = wr*64 + mi*16 + q*4 + reg.
    // sim = acc / 127^2; exp(sim * 2). Row-partials -> slot 2*cb+wc;
    // transpose col-partials -> slot 2*rb+wr. Row r of block i receives
    // slots {2c,2c+1 : c>=i} ∪ {2c,2c+1 : c<i} = all 128, disjoint.
    const float esc = 2.0f / 16129.0f;  // (1/T) / 127^2
    float colsum[4];
#pragma unroll
    for (int ni = 0; ni < 4; ++ni) colsum[ni] = 0.f;

#pragma unroll
    for (int mi = 0; mi < 4; ++mi) {
#pragma unroll
        for (int reg = 0; reg < 4; ++reg) {
            const int grow = rb * 128 + wr * 64 + mi * 16 + (q << 2) + reg;
            float rs = 0.f;
#pragma unroll
            for (int ni = 0; ni < 4; ++ni) {
                const int gcol = cb * 128 + wc * 64 + ni * 16 + cm;
                const float e =
                    (grow == gcol) ? 0.f : __expf((float)acc[mi][ni][reg] * esc);
                rs += e;
                colsum[ni] += e;
            }
            rs += __shfl_xor(rs, 1);
            rs += __shfl_xor(rs, 2);
            rs += __shfl_xor(rs, 4);
            rs += __shfl_xor(rs, 8);
            if (cm == 0) partial[(size_t)(2 * cb + wc) * NN + grow] = rs;
        }
    }

    if (rb != cb) {
#pragma unroll
        for (int ni = 0; ni < 4; ++ni) {
            colsum[ni] += __shfl_xor(colsum[ni], 16);  // fold q
            colsum[ni] += __shfl_xor(colsum[ni], 32);
        }
        if (q == 0) {
#pragma unroll
            for (int ni = 0; ni < 4; ++ni)
                partial[(size_t)(2 * rb + wr) * NN + cb * 128 + wc * 64 + ni * 16 + cm] =
                    colsum[ni];
        }
    }
}

// Kernel 3: per-row denom -> per-row loss -> 64 block sums. 2 threads/row.
__global__ void reduce_rows_kernel(const float* __restrict__ partial,
                                   const float* __restrict__ pos,
                                   float* __restrict__ bsum) {
    const int g = blockIdx.x * 256 + threadIdx.x;  // 64 x 256 = 16384
    const int r = g >> 1;
    const int half = g & 1;
    float s0 = 0.f, s1 = 0.f, s2 = 0.f, s3 = 0.f;
    for (int kb = half * 64; kb < half * 64 + 64; kb += 4) {
        s0 += partial[(size_t)(kb + 0) * NN + r];
        s1 += partial[(size_t)(kb + 1) * NN + r];
        s2 += partial[(size_t)(kb + 2) * NN + r];
        s3 += partial[(size_t)(kb + 3) * NN + r];
    }
    float s = (s0 + s1) + (s2 + s3);
    s += __shfl_xor(s, 1);  // both lanes of the pair hold the full row sum
    float v = __logf(s) - pos[r & (B_ROWS - 1)] * 2.0f;  // counted twice; *0.5 below
    v = wave_reduce_sum(v);
    __shared__ float red[4];
    const int lane = threadIdx.x & 63, wv = threadIdx.x >> 6;
    if (lane == 0) red[wv] = v;
    __syncthreads();
    if (threadIdx.x == 0)
        bsum[blockIdx.x] = (red[0] + red[1] + red[2] + red[3]) * 0.5f;
}

// Kernel 4: final scalar
__global__ void final_kernel(const float* __restrict__ bsum,
                             float* __restrict__ out) {
    float s = bsum[threadIdx.x];
    s = wave_reduce_sum(s);
    if (threadIdx.x == 0) out[0] = s * (1.0f / NN);
}

extern "C" void kernel_launch(void* const* d_in, const int* in_sizes, int n_in,
                              void* d_out, int out_size, void* d_ws, size_t ws_size,
                              hipStream_t stream) {
    const float* p1 = (const float*)d_in[0];
    const float* p2 = (const float*)d_in[1];
    char* ws = (char*)d_ws;
    signed char* rep = (signed char*)ws;                      // 8 MiB (i8)
    float* partial = (float*)(ws + (size_t)8 * 1024 * 1024);  // 4 MiB (128 x 8192)
    float* pos = (float*)(ws + (size_t)12 * 1024 * 1024);     // 16 KiB
    float* bsum = (float*)(ws + (size_t)12 * 1024 * 1024 + 16384);  // 256 B
    float* out = (float*)d_out;

    norm_pos_kernel<<<1024, 256, 0, stream>>>(p1, p2, rep, pos);
    gemm_kernel<<<2080, 256, 0, stream>>>(rep, partial);
    reduce_rows_kernel<<<64, 256, 0, stream>>>(partial, pos, bsum);
    final_kernel<<<1, 64, 0, stream>>>(bsum, out);
}

// Round 7
// 129.412 us; speedup vs baseline: 1.1571x; 1.0350x over previous
//
#include <hip/hip_runtime.h>
#include <hip/hip_bf16.h>
#include <cstdint>

#define B_ROWS 4096
#define DIM 1024
#define NN 8192  // 2*B

typedef int v4i __attribute__((ext_vector_type(4)));

__device__ __forceinline__ float wave_reduce_sum(float v) {
    v += __shfl_xor(v, 1);
    v += __shfl_xor(v, 2);
    v += __shfl_xor(v, 4);
    v += __shfl_xor(v, 8);
    v += __shfl_xor(v, 16);
    v += __shfl_xor(v, 32);
    return v;
}

__device__ __forceinline__ void gld_lds16(const void* g, void* l) {
    __builtin_amdgcn_global_load_lds(
        (__attribute__((address_space(1))) void*)(uintptr_t)g,
        (__attribute__((address_space(3))) void*)l, 16, 0, 0);
}

// Kernel 1: L2-normalize + positives, ONE WAVE PER ROW-PAIR. No LDS/barriers.
// rep is SIGNED i8: round(127 * normalized). |x̂| <= ~0.16 for N(0,1) data at
// D=1024, so no clamp needed; i32 MFMA accumulation is exact.
// R23: also zeroes denom[8192] and out[0] (frees two downstream dispatches).
__global__ void norm_pos_kernel(const float* __restrict__ p1,
                                const float* __restrict__ p2,
                                signed char* __restrict__ rep,
                                float* __restrict__ pos,
                                float* __restrict__ denom,
                                float* __restrict__ out) {
    if (blockIdx.x < 32) denom[blockIdx.x * 256 + threadIdx.x] = 0.f;
    if (blockIdx.x == 0 && threadIdx.x == 0) out[0] = 0.f;
    const int wv = threadIdx.x >> 6, lane = threadIdx.x & 63;
    const int i = blockIdx.x * 4 + wv;  // 0..4095
    const float4* ap = (const float4*)(p1 + (size_t)i * DIM);
    const float4* bp = (const float4*)(p2 + (size_t)i * DIM);
    float4 a[4], b[4];
#pragma unroll
    for (int c = 0; c < 4; ++c) { a[c] = ap[lane + 64 * c]; b[c] = bp[lane + 64 * c]; }
    float s1 = 0.f, s2 = 0.f, dp = 0.f;
#pragma unroll
    for (int c = 0; c < 4; ++c) {
        s1 += a[c].x * a[c].x + a[c].y * a[c].y + a[c].z * a[c].z + a[c].w * a[c].w;
        s2 += b[c].x * b[c].x + b[c].y * b[c].y + b[c].z * b[c].z + b[c].w * b[c].w;
        dp += a[c].x * b[c].x + a[c].y * b[c].y + a[c].z * b[c].z + a[c].w * b[c].w;
    }
    s1 = wave_reduce_sum(s1);
    s2 = wave_reduce_sum(s2);
    dp = wave_reduce_sum(dp);
    const float sc1 = rsqrtf(s1) * 127.0f, sc2 = rsqrtf(s2) * 127.0f;
    char4* o1 = (char4*)(rep + (size_t)i * DIM);
    char4* o2 = (char4*)(rep + (size_t)(i + B_ROWS) * DIM);
#pragma unroll
    for (int c = 0; c < 4; ++c) {
        char4 u1, u2;
        u1.x = (signed char)__float2int_rn(a[c].x * sc1);
        u1.y = (signed char)__float2int_rn(a[c].y * sc1);
        u1.z = (signed char)__float2int_rn(a[c].z * sc1);
        u1.w = (signed char)__float2int_rn(a[c].w * sc1);
        u2.x = (signed char)__float2int_rn(b[c].x * sc2);
        u2.y = (signed char)__float2int_rn(b[c].y * sc2);
        u2.z = (signed char)__float2int_rn(b[c].z * sc2);
        u2.w = (signed char)__float2int_rn(b[c].w * sc2);
        o1[lane + 64 * c] = u1;
        o2[lane + 64 * c] = u2;
    }
    if (lane == 0) pos[i] = dp * rsqrtf(s1) * rsqrtf(s2);
}

// Kernel 2 (R23): R4's measured-best gemm (256x128 rect tiles, 4 waves of
// 64x128, 16x16x64 i8, m201-phased K-loop, 56.2 us) with the epilogue
// switched from partial-array stores to DEVICE-SCOPE float atomicAdd into
// denom[8192].
//
// WHY: R0-R6 exonerated schedule (5 variants), tile shape (2), MFMA shape
// (2), occupancy (2), and L2 locality (R6: FETCH 63->20 MB, time FLAT) —
// the gemm sits at 56-70 us with MFMA-busy constant ~13.8 us. That is the
// m233 structural plateau; further gemm rounds are low-EV. The unattended
// budget is the ~72 us OUTSIDE the gemm (total 134 - gemm 62). This round
// deletes the partial array (4 MB write + 4 MB read) and one kernel launch:
// gemm atomically accumulates exp-sums per row (atomics: ~676K over 8192
// addresses, ~82/address spread over 56 us — negligible contention; float
// atomicAdd on global is device-scope by default).
//
// Tiling (R4, verified): tiles (R,C): rows [256R,..+256), cols [128C,..+128),
// set {C>=2R}; 1056 tiles, start(R)=R*(65-R). Coverage: pair (i,j) counted
// by ROWSUM of its primary tile when in set; else by COLSUM of the mirror
// tile, predicated per-wave (2rb+(wv>>1) < 2(cb>>1), wave-uniform).
// Diagonal masked in-place. With atomics, !pred waves simply don't add.
// K-perm trick: lane (cm,q) reads seg (q^fsw); A-lane and B-lane hold the
// same 16 global-k bytes in the same order -> contraction invariant.
__global__ __launch_bounds__(256, 2) void gemm_kernel(const signed char* __restrict__ rep,
                                                      float* __restrict__ denom) {
    // XCD-chunked swizzle (1056 = 8*132, bijective)
    const int bid0 = blockIdx.x;
    const int bid = (bid0 & 7) * 132 + (bid0 >> 3);
    // decode: start(R) = R*(65-R), count 64-2R
    int rb = (int)((65.0f - sqrtf(4225.0f - 4.0f * (float)bid)) * 0.5f);
    while ((rb + 1) * (64 - rb) <= bid) ++rb;
    while (rb * (65 - rb) > bid) --rb;
    const int cb = 2 * rb + (bid - rb * (65 - rb));

    __shared__ __align__(16) signed char As[3][16384];  // 48 KB (256 rows x 64)
    __shared__ __align__(16) signed char Bs[3][8192];   // 24 KB (128 rows x 64)
    const int t = threadIdx.x;
    const int lane = t & 63;
    const int wv = t >> 6;     // 0..3: wave owns rows wv*64..wv*64+63 of the tile
    const int cm = lane & 15;  // frag m,n index
    const int q = lane >> 4;   // frag k-quarter

    // staging source
    const int sr = t >> 2;
    const int sg = (t & 3) ^ ((sr >> 1) & 3);
    const signed char* aS = rep + (size_t)(rb * 256 + sr) * DIM + sg * 16;
    const signed char* bS = rep + (size_t)(cb * 128 + sr) * DIM + sg * 16;

    // fragment read offsets (k-invariant)
    const int fsw = (cm >> 1) & 3;
    const int aOff = wv * 4096 + cm * 64 + ((q ^ fsw) << 4);
    const int bOff = cm * 64 + ((q ^ fsw) << 4);

    v4i acc[4][8];
#pragma unroll
    for (int i = 0; i < 4; ++i)
#pragma unroll
        for (int j = 0; j < 8; ++j) acc[i][j] = (v4i){0, 0, 0, 0};

    // half-STAGE: part 0 = A rows 0..191; part 1 = A rows 192..255 + B.
    auto STAGE_HALF = [&](signed char* Ad, signed char* Bd, int kk, int part) {
        const signed char* a0 = aS + kk * 64;
        const signed char* b0 = bS + kk * 64;
        if (part == 0) {
            gld_lds16(a0, Ad + t * 16);                             // A rows 0..63
            gld_lds16(a0 + (size_t)64 * DIM, Ad + t * 16 + 4096);   // 64..127
            gld_lds16(a0 + (size_t)128 * DIM, Ad + t * 16 + 8192);  // 128..191
        } else {
            gld_lds16(a0 + (size_t)192 * DIM, Ad + t * 16 + 12288); // 192..255
            gld_lds16(b0, Bd + t * 16);                             // B rows 0..63
            gld_lds16(b0 + (size_t)64 * DIM, Bd + t * 16 + 4096);   // 64..127
        }
    };

    // Prologue: stage tiles 0 and 1; wait tile 0 (oldest 6) then barrier.
    STAGE_HALF(As[0], Bs[0], 0, 0);
    STAGE_HALF(As[0], Bs[0], 0, 1);
    STAGE_HALF(As[1], Bs[1], 1, 0);
    STAGE_HALF(As[1], Bs[1], 1, 1);
    asm volatile("s_waitcnt vmcnt(6)" ::: "memory");
    __builtin_amdgcn_s_barrier();

#pragma unroll
    for (int kk = 0; kk < 16; ++kk) {
        const signed char* Ab = As[kk % 3];
        const signed char* Bb = Bs[kk % 3];
        signed char* Ast = As[(kk + 2) % 3];
        signed char* Bst = Bs[(kk + 2) % 3];
        const bool do_stage = (kk < 14);

        // ---- phase A: read af0-3 + bf0-3, stage half, MFMA ni 0-3 ----
        v4i af[4], bf[4];
#pragma unroll
        for (int mi = 0; mi < 4; ++mi) af[mi] = *(const v4i*)(Ab + aOff + mi * 1024);
#pragma unroll
        for (int ni = 0; ni < 4; ++ni) bf[ni] = *(const v4i*)(Bb + bOff + ni * 1024);
        if (do_stage) STAGE_HALF(Ast, Bst, kk + 2, 0);
        __builtin_amdgcn_sched_barrier(0);
        __builtin_amdgcn_s_barrier();
        asm volatile("s_waitcnt lgkmcnt(0)" ::: "memory");
        __builtin_amdgcn_sched_barrier(0);
        __builtin_amdgcn_s_setprio(1);
#pragma unroll
        for (int mi = 0; mi < 4; ++mi)
#pragma unroll
            for (int ni = 0; ni < 4; ++ni)
                acc[mi][ni] = __builtin_amdgcn_mfma_i32_16x16x64_i8(
                    af[mi], bf[ni], acc[mi][ni], 0, 0, 0);
        __builtin_amdgcn_s_setprio(0);
        __builtin_amdgcn_sched_barrier(0);
        __builtin_amdgcn_s_barrier();

        // ---- phase B: read bf4-7, stage other half, MFMA ni 4-7 ----
#pragma unroll
        for (int ni = 0; ni < 4; ++ni)
            bf[ni] = *(const v4i*)(Bb + bOff + 4096 + ni * 1024);
        if (do_stage) STAGE_HALF(Ast, Bst, kk + 2, 1);
        __builtin_amdgcn_sched_barrier(0);
        __builtin_amdgcn_s_barrier();
        asm volatile("s_waitcnt lgkmcnt(0)" ::: "memory");
        __builtin_amdgcn_sched_barrier(0);
        __builtin_amdgcn_s_setprio(1);
#pragma unroll
        for (int mi = 0; mi < 4; ++mi)
#pragma unroll
            for (int ni = 0; ni < 4; ++ni)
                acc[mi][4 + ni] = __builtin_amdgcn_mfma_i32_16x16x64_i8(
                    af[mi], bf[ni], acc[mi][4 + ni], 0, 0, 0);
        __builtin_amdgcn_s_setprio(0);
        __builtin_amdgcn_sched_barrier(0);

        // ---- tile end: counted wait for next buffer, then block-wide sync.
        if (kk < 14) {
            asm volatile("s_waitcnt vmcnt(6)" ::: "memory");  // tile kk+1 resident
            __builtin_amdgcn_s_barrier();
        } else if (kk == 14) {
            asm volatile("s_waitcnt vmcnt(0)" ::: "memory");  // tile 15 resident
            __builtin_amdgcn_s_barrier();
        }
    }

    // Epilogue (R23): atomic accumulation into denom[8192].
    // C/D: col = ni*16 + cm (tile-local), row = wv*64 + mi*16 + q*4 + reg.
    const float esc = 2.0f / 16129.0f;  // (1/T) / 127^2
    float colsum[8];
#pragma unroll
    for (int ni = 0; ni < 8; ++ni) colsum[ni] = 0.f;

#pragma unroll
    for (int mi = 0; mi < 4; ++mi) {
#pragma unroll
        for (int reg = 0; reg < 4; ++reg) {
            const int grow = rb * 256 + wv * 64 + mi * 16 + (q << 2) + reg;
            float rs = 0.f;
#pragma unroll
            for (int ni = 0; ni < 8; ++ni) {
                const int gcol = cb * 128 + ni * 16 + cm;
                const float e =
                    (grow == gcol) ? 0.f : __expf((float)acc[mi][ni][reg] * esc);
                rs += e;
                colsum[ni] += e;
            }
            rs += __shfl_xor(rs, 1);
            rs += __shfl_xor(rs, 2);
            rs += __shfl_xor(rs, 4);
            rs += __shfl_xor(rs, 8);
            if (cm == 0) atomicAdd(denom + grow, rs);  // rowsum
        }
    }

    // colsum: include only pairs whose primary tile is NOT in the set.
    const bool pred = (2 * rb + (wv >> 1)) < 2 * (cb >> 1);
#pragma unroll
    for (int ni = 0; ni < 8; ++ni) {
        colsum[ni] += __shfl_xor(colsum[ni], 16);  // fold q (rows)
        colsum[ni] += __shfl_xor(colsum[ni], 32);
    }
    if (pred && q == 0) {
#pragma unroll
        for (int ni = 0; ni < 8; ++ni)
            atomicAdd(denom + cb * 128 + ni * 16 + cm, colsum[ni]);
    }
}

// Kernel 3 (R23): finish — one thread per row: loss_r = log(denom_r) - 2*pos,
// block-reduce, single atomicAdd per block into out (out zeroed by kernel 1).
__global__ void finish_kernel(const float* __restrict__ denom,
                              const float* __restrict__ pos,
                              float* __restrict__ out) {
    const int r = blockIdx.x * 256 + threadIdx.x;  // 32 x 256 = 8192
    float v = __logf(denom[r]) - pos[r & (B_ROWS - 1)] * 2.0f;
    v = wave_reduce_sum(v);
    __shared__ float red[4];
    const int lane = threadIdx.x & 63, wv = threadIdx.x >> 6;
    if (lane == 0) red[wv] = v;
    __syncthreads();
    if (threadIdx.x == 0)
        atomicAdd(out, (red[0] + red[1] + red[2] + red[3]) * (1.0f / NN));
}

extern "C" void kernel_launch(void* const* d_in, const int* in_sizes, int n_in,
                              void* d_out, int out_size, void* d_ws, size_t ws_size,
                              hipStream_t stream) {
    const float* p1 = (const float*)d_in[0];
    const float* p2 = (const float*)d_in[1];
    char* ws = (char*)d_ws;
    signed char* rep = (signed char*)ws;                        // 8 MiB (i8)
    float* pos = (float*)(ws + (size_t)8 * 1024 * 1024);        // 16 KiB
    float* denom = (float*)(ws + (size_t)8 * 1024 * 1024 + 16384);  // 32 KiB
    float* out = (float*)d_out;

    norm_pos_kernel<<<1024, 256, 0, stream>>>(p1, p2, rep, pos, denom, out);
    gemm_kernel<<<1056, 256, 0, stream>>>(rep, denom);
    finish_kernel<<<32, 256, 0, stream>>>(denom, pos, out);
}